// Round 7
// baseline (6046.519 us; speedup 1.0000x reference)
//
#include <hip/hip_runtime.h>
#include <hip/hip_bf16.h>

typedef __attribute__((ext_vector_type(8))) __bf16 bf16x8;
typedef __attribute__((ext_vector_type(4))) float f32x4;

static constexpr int BB = 64;    // batch
static constexpr int SS = 512;   // seq len
static constexpr int IN = 512;   // input dim
static constexpr int HH = 1024;  // hidden
static constexpr int OO = 512;   // output dim
static constexpr int KK = 1536;  // H + I (combined recurrent K)
static constexpr int G4 = 4096;  // 4*H
static constexpr int NBLK = 256; // recurrent blocks (1 per CU)
static constexpr int COLS = 16;  // gate-cols per recurrent block (G4/NBLK)
static constexpr int HCPB = 4;   // h-cols per recurrent block (HH/NBLK)

__device__ __forceinline__ f32x4 mfma16(bf16x8 a, bf16x8 b, f32x4 c) {
  return __builtin_amdgcn_mfma_f32_16x16x32_bf16(a, b, c, 0, 0, 0);
}
__device__ __forceinline__ float sigm(float x) { return 1.f / (1.f + __expf(-x)); }

// Gate-col permutation: p = n*16 + g*4 + r  <->  gate g, hcol = n*4 + r.
// Recurrent block n owns permuted cols [n*16, n*16+16).

__global__ void k_convw(const float* Wf, const float* Wi, const float* Wo, const float* Wc,
                        const float* bfv, const float* biv, const float* bov, const float* bcv,
                        __bf16* Wcomb, float* biasp) {
  int p = blockIdx.x;                       // 0..4095
  int g = (p >> 2) & 3;
  int hcol = ((p >> 4) << 2) | (p & 3);
  const float* Wg = (g == 0) ? Wf : (g == 1) ? Wi : (g == 2) ? Wo : Wc;
  const float* bg = (g == 0) ? bfv : (g == 1) ? biv : (g == 2) ? bov : bcv;
  const float* src = Wg + (size_t)hcol * KK;
  for (int k = threadIdx.x; k < KK; k += 256) Wcomb[(size_t)p * KK + k] = (__bf16)src[k];
  if (threadIdx.x == 0) biasp[p] = bg[hcol];
}

// xb[(t*64+b)*512 + k] = bf16(x[b][t][k])   (t-major rows for the recurrent A-fragments)
__global__ void k_convx(const float* x, __bf16* xb) {
  size_t idx = (size_t)blockIdx.x * 256 + threadIdx.x;  // 16,777,216
  int k = idx & 511;
  size_t row = idx >> 9;
  int t = (int)(row >> 6), b = (int)(row & 63);
  xb[idx] = (__bf16)x[((size_t)b * SS + t) * IN + k];
}

__global__ void k_convfc(const float* Wfc, __bf16* Wfcb) {
  size_t i = (size_t)blockIdx.x * 256 + threadIdx.x;  // 524,288
  Wfcb[i] = (__bf16)Wfc[i];
}

__global__ void k_zeroh0(__bf16* hsb) {
  size_t i = (size_t)blockIdx.x * 256 + threadIdx.x;  // 65,536 (slot 0 = h_{-1} = 0)
  hsb[i] = (__bf16)0.f;
}

__global__ void k_diag(float* out, float v) { out[0] = v; }

// Persistent recurrent kernel: 256 blocks x 256 thr. K-SPLIT ACROSS WAVES:
// wave w owns K-chunks [12w, 12w+12) (chunk = 32 k-values; chunks 0..31 = h, 32..47 = x),
// computing partial sums for ALL 64 rows x 16 cols; partials reduced via LDS (dbuf).
// Weight B-fragments are read from LDS ONCE per chunk (was 4x redundant).
// Wave 3's range is pure-x -> it never waits on flags -> it is the PUBLISHER:
// reduce + activations + WT h-store + own-wave vmcnt drain + flag, decoupled from
// waves 0-2 which immediately run ahead into step t+1 (x-MFMA + their flag subset).
// One __syncthreads per step (partials ready). Publication: agent-scope sc1 stores
// (write-through, LLC authoritative); consumers' plain loads hit fresh lines only.
__global__ __launch_bounds__(256) void k_lstm(const __bf16* __restrict__ Wcomb,
                                              const __bf16* __restrict__ xb,
                                              const float* __restrict__ biasp,
                                              __bf16* __restrict__ hsb,
                                              float* __restrict__ tail,
                                              unsigned* __restrict__ flags) {
  const int n = blockIdx.x;
  const int tid = threadIdx.x;
  const int w = tid >> 6, l = tid & 63;
  const int l16 = l & 15, lk = l >> 4;
  __shared__ __bf16 wl[48 * 512];        // 48 KB: chunk-major weight fragments
  __shared__ float gt2[2][4][64][21];    // 42 KB: per-wave partials, double-buffered, padded
  // --- preload weight slice into LDS, fragment-major (chunk-major) ---
  for (int i = tid; i < COLS * (KK / 8); i += 256) {  // 16*192 = 3072
    int c = i / 192, kch = i % 192;
    bf16x8 v = *(const bf16x8*)(Wcomb + ((size_t)(n * COLS + c)) * KK + kch * 8);
    int chunk = kch >> 2, lkw = kch & 3;
    *(bf16x8*)(wl + ((chunk * 64 + lkw * 16 + c) << 3)) = v;
  }
  float bfl[16];
#pragma unroll
  for (int c = 0; c < 16; ++c) bfl[c] = biasp[n * COLS + c];  // uniform per block
  float creg[4] = {0.f, 0.f, 0.f, 0.f};  // c-state: lives in wave 3, lane l = batch row
  __syncthreads();
  const int c0 = 12 * w, c1 = c0 + 12;              // this wave's chunk range
  const int hc1 = (c1 < 32) ? c1 : 32;              // end of h-chunks
  const int xc0 = (c0 > 32) ? c0 : 32;              // start of x-chunks
  const int p0 = 8 * c0;                            // producer flag range [p0,p1)
  const int p1 = 8 * ((hc1 > c0) ? hc1 : c0);
  const __bf16* wlane = wl + ((lk * 16 + l16) << 3);
  const f32x4 vz = {0.f, 0.f, 0.f, 0.f};
  for (int t = 0; t < SS; ++t) {
    const __bf16* hp = hsb + (size_t)t * (BB * HH);
    const __bf16* xp = xb + (size_t)t * (BB * IN);
    f32x4 acc0 = vz, acc1 = vz, acc2 = vz, acc3 = vz;  // 4 row-tiles (M=64)
    // ---- x-chunks first (no dependency on h_t) ----
    for (int c = xc0; c < c1; ++c) {
      bf16x8 bv = *(const bf16x8*)(wlane + c * 512);
      const __bf16* ax = xp + (size_t)l16 * IN + (c - 32) * 32 + lk * 8;
      acc0 = mfma16(*(const bf16x8*)(ax), bv, acc0);
      acc1 = mfma16(*(const bf16x8*)(ax + 16 * IN), bv, acc1);
      acc2 = mfma16(*(const bf16x8*)(ax + 32 * IN), bv, acc2);
      acc3 = mfma16(*(const bf16x8*)(ax + 48 * IN), bv, acc3);
    }
    // ---- wait for this wave's h-producer subset, then h-chunks ----
    if (p1 > p0) {
      const unsigned tgt = (unsigned)t;
      for (;;) {
        bool ok = true;
        if (p0 + l < p1)
          ok &= (__hip_atomic_load(&flags[p0 + l], __ATOMIC_RELAXED, __HIP_MEMORY_SCOPE_AGENT) >= tgt);
        if (p0 + 64 + l < p1)
          ok &= (__hip_atomic_load(&flags[p0 + 64 + l], __ATOMIC_RELAXED, __HIP_MEMORY_SCOPE_AGENT) >= tgt);
        if (__all((int)ok)) break;
        __builtin_amdgcn_s_sleep(1);
      }
      asm volatile("" ::: "memory");  // no h-load hoisting above the flag check
      for (int c = c0; c < hc1; ++c) {
        bf16x8 bv = *(const bf16x8*)(wlane + c * 512);
        const __bf16* ah = hp + (size_t)l16 * HH + c * 32 + lk * 8;
        acc0 = mfma16(*(const bf16x8*)(ah), bv, acc0);
        acc1 = mfma16(*(const bf16x8*)(ah + 16 * HH), bv, acc1);
        acc2 = mfma16(*(const bf16x8*)(ah + 32 * HH), bv, acc2);
        acc3 = mfma16(*(const bf16x8*)(ah + 48 * HH), bv, acc3);
      }
    }
    // ---- spill partials (dbuf: waves may be one step apart) ----
    const int buf = t & 1;
#pragma unroll
    for (int q = 0; q < 4; ++q) {
      gt2[buf][w][lk * 4 + q][l16] = acc0[q];       // D: row=lk*4+q, col=l16
      gt2[buf][w][16 + lk * 4 + q][l16] = acc1[q];
      gt2[buf][w][32 + lk * 4 + q][l16] = acc2[q];
      gt2[buf][w][48 + lk * 4 + q][l16] = acc3[q];
    }
    __syncthreads();  // the only per-step block barrier
    // ---- wave 3 (pure-x wave): reduce + activations + publish ----
    if (w == 3) {
      float hv4[4];
#pragma unroll
      for (int rr = 0; rr < 4; ++rr) {
        float sf = gt2[buf][0][l][rr]      + gt2[buf][1][l][rr]      + gt2[buf][2][l][rr]      + gt2[buf][3][l][rr]      + bfl[rr];
        float si = gt2[buf][0][l][4 + rr]  + gt2[buf][1][l][4 + rr]  + gt2[buf][2][l][4 + rr]  + gt2[buf][3][l][4 + rr]  + bfl[4 + rr];
        float so = gt2[buf][0][l][8 + rr]  + gt2[buf][1][l][8 + rr]  + gt2[buf][2][l][8 + rr]  + gt2[buf][3][l][8 + rr]  + bfl[8 + rr];
        float sg = gt2[buf][0][l][12 + rr] + gt2[buf][1][l][12 + rr] + gt2[buf][2][l][12 + rr] + gt2[buf][3][l][12 + rr] + bfl[12 + rr];
        creg[rr] = sigm(sf) * creg[rr] + sigm(si) * tanhf(sg);
        hv4[rr] = sigm(so) * tanhf(creg[rr]);
      }
      unsigned long long u0 = (unsigned short)__builtin_bit_cast(unsigned short, (__bf16)hv4[0]);
      unsigned long long u1 = (unsigned short)__builtin_bit_cast(unsigned short, (__bf16)hv4[1]);
      unsigned long long u2 = (unsigned short)__builtin_bit_cast(unsigned short, (__bf16)hv4[2]);
      unsigned long long u3 = (unsigned short)__builtin_bit_cast(unsigned short, (__bf16)hv4[3]);
      unsigned long long pk = u0 | (u1 << 16) | (u2 << 32) | (u3 << 48);
      unsigned long long* dst =
          (unsigned long long*)(hsb + (size_t)(t + 1) * (BB * HH) + (size_t)l * HH + n * HCPB);
      __hip_atomic_store(dst, pk, __ATOMIC_RELAXED, __HIP_MEMORY_SCOPE_AGENT);  // sc1 WT
      if (t == SS - 1) {
#pragma unroll
        for (int rr = 0; rr < 4; ++rr) {
          tail[(size_t)l * HH + n * HCPB + rr] = hv4[rr];
          tail[(size_t)BB * HH + (size_t)l * HH + n * HCPB + rr] = creg[rr];
        }
      }
      // drain THIS wave's stores (only wave 3 stored h), then signal
      asm volatile("s_waitcnt vmcnt(0)" ::: "memory");
      if (t + 1 < SS && l == 0)
        __hip_atomic_store(&flags[n], (unsigned)(t + 1), __ATOMIC_RELAXED, __HIP_MEMORY_SCOPE_AGENT);
    }
  }
}

// GEMM-2: out[r=b*S+t][col] = hs[t+1][b][:] . Wfc[col][:] + bfc[col]  (M=32768,N=512,K=1024)
__global__ __launch_bounds__(256) void k_gemm_out(const __bf16* __restrict__ hsb,
                                                  const __bf16* __restrict__ Wfcb,
                                                  const float* __restrict__ bfc,
                                                  float* __restrict__ out) {
  int w = threadIdx.x >> 6, l = threadIdx.x & 63;
  int l16 = l & 15, lk = l >> 4;
  int Mbase = blockIdx.x * 64, Nbase = blockIdx.y * 64;
  int rA = Mbase + w * 16 + l16;
  int bb = rA >> 9, tt = rA & 511;
  const __bf16* Ap = hsb + ((size_t)(tt + 1) * BB + bb) * HH + lk * 8;
  const __bf16* Bp[4];
#pragma unroll
  for (int jt = 0; jt < 4; ++jt)
    Bp[jt] = Wfcb + ((size_t)(Nbase + jt * 16 + l16)) * HH + lk * 8;
  const f32x4 vz = {0.f, 0.f, 0.f, 0.f};
  f32x4 acc[4] = {vz, vz, vz, vz};
  for (int kc = 0; kc < HH; kc += 32) {
    bf16x8 a = *(const bf16x8*)(Ap + kc);
#pragma unroll
    for (int jt = 0; jt < 4; ++jt) {
      bf16x8 bv = *(const bf16x8*)(Bp[jt] + kc);
      acc[jt] = mfma16(a, bv, acc[jt]);
    }
  }
#pragma unroll
  for (int jt = 0; jt < 4; ++jt) {
    int col = Nbase + jt * 16 + l16;
    float badd = bfc[col];
#pragma unroll
    for (int q = 0; q < 4; ++q) {
      int rD = Mbase + w * 16 + lk * 4 + q;
      out[(size_t)rD * OO + col] = acc[jt][q] + badd;
    }
  }
}

extern "C" void kernel_launch(void* const* d_in, const int* in_sizes, int n_in,
                              void* d_out, int out_size, void* d_ws, size_t ws_size,
                              hipStream_t stream) {
  const float* x = (const float*)d_in[0];
  const float* Wf = (const float*)d_in[1];
  const float* Wi = (const float*)d_in[2];
  const float* Wo = (const float*)d_in[3];
  const float* Wc = (const float*)d_in[4];
  const float* bfv = (const float*)d_in[5];
  const float* biv = (const float*)d_in[6];
  const float* bov = (const float*)d_in[7];
  const float* bcv = (const float*)d_in[8];
  const float* Wfc = (const float*)d_in[9];
  const float* bfc = (const float*)d_in[10];
  float* out = (float*)d_out;

  char* ws = (char*)d_ws;
  size_t off = 0;
  auto take = [&](size_t bytes) -> char* {
    off = (off + 255) & ~(size_t)255;
    char* p = ws + off;
    off += bytes;
    return p;
  };
  __bf16* Wcomb = (__bf16*)take((size_t)G4 * KK * 2);            // 12 MB
  __bf16* Wfcb = (__bf16*)take((size_t)OO * HH * 2);             // 1 MB
  float* biasp = (float*)take((size_t)G4 * 4);                   // 16 KB
  unsigned* flags = (unsigned*)take(NBLK * 4);                   // per-block flags (1 KB)
  __bf16* xb = (__bf16*)take((size_t)BB * SS * IN * 2);          // 32 MB
  __bf16* hsb = (__bf16*)take((size_t)(SS + 1) * BB * HH * 2);   // 64.1 MB
  if (off > ws_size) {
    hipLaunchKernelGGL(k_diag, dim3(1), dim3(1), 0, stream, out,
                       1.0e6f + (float)(ws_size >> 20));
    return;
  }

  hipMemsetAsync(flags, 0, NBLK * 4, stream);  // reset flags each launch (graph-replay-safe)
  hipLaunchKernelGGL(k_convw, dim3(G4), dim3(256), 0, stream,
                     Wf, Wi, Wo, Wc, bfv, biv, bov, bcv, Wcomb, biasp);
  hipLaunchKernelGGL(k_convx, dim3((BB * SS * IN) / 256), dim3(256), 0, stream, x, xb);
  hipLaunchKernelGGL(k_convfc, dim3((OO * HH) / 256), dim3(256), 0, stream, Wfc, Wfcb);
  hipLaunchKernelGGL(k_zeroh0, dim3((BB * HH) / 256), dim3(256), 0, stream, hsb);

  float* tail = out + (size_t)BB * SS * OO;
  void* args[] = {(void*)&Wcomb, (void*)&xb, (void*)&biasp, (void*)&hsb,
                  (void*)&tail, (void*)&flags};
  hipError_t cerr = hipLaunchCooperativeKernel((const void*)k_lstm, dim3(NBLK), dim3(256),
                                               args, 0, stream);
  if (cerr != hipSuccess) {
    hipLaunchKernelGGL(k_diag, dim3(1), dim3(1), 0, stream, out,
                       2.0e6f + (float)(int)cerr);
    return;
  }

  hipLaunchKernelGGL(k_gemm_out, dim3((BB * SS) / 64, OO / 64), dim3(256), 0, stream,
                     hsb, Wfcb, bfc, out);
}

// Round 8
// 3852.373 us; speedup vs baseline: 1.5696x; 1.5696x over previous
//
#include <hip/hip_runtime.h>
#include <hip/hip_bf16.h>

typedef __attribute__((ext_vector_type(8))) __bf16 bf16x8;
typedef __attribute__((ext_vector_type(4))) float f32x4;

static constexpr int BB = 64;    // batch
static constexpr int SS = 512;   // seq len
static constexpr int IN = 512;   // input dim
static constexpr int HH = 1024;  // hidden
static constexpr int OO = 512;   // output dim
static constexpr int KK = 1536;  // H + I (combined recurrent K)
static constexpr int G4 = 4096;  // 4*H
static constexpr int NBLK = 256; // recurrent blocks (1 per CU)
static constexpr int COLS = 16;  // gate-cols per recurrent block (G4/NBLK)
static constexpr int HCPB = 4;   // h-cols per recurrent block (HH/NBLK)

__device__ __forceinline__ f32x4 mfma16(bf16x8 a, bf16x8 b, f32x4 c) {
  return __builtin_amdgcn_mfma_f32_16x16x32_bf16(a, b, c, 0, 0, 0);
}
__device__ __forceinline__ float sigm(float x) { return 1.f / (1.f + __expf(-x)); }
// branch-free tanh: 1 - 2/(1+e^{2x}); exact at saturation (e^inf -> 1, e^-inf -> -1)
__device__ __forceinline__ float tanh_f(float x) { return 1.f - 2.f / (1.f + __expf(2.f * x)); }

// Gate-col permutation: p = n*16 + g*4 + r  <->  gate g, hcol = n*4 + r.
// Recurrent block n owns permuted cols [n*16, n*16+16).

__global__ void k_convw(const float* Wf, const float* Wi, const float* Wo, const float* Wc,
                        const float* bfv, const float* biv, const float* bov, const float* bcv,
                        __bf16* Wcomb, float* biasp) {
  int p = blockIdx.x;                       // 0..4095
  int g = (p >> 2) & 3;
  int hcol = ((p >> 4) << 2) | (p & 3);
  const float* Wg = (g == 0) ? Wf : (g == 1) ? Wi : (g == 2) ? Wo : Wc;
  const float* bg = (g == 0) ? bfv : (g == 1) ? biv : (g == 2) ? bov : bcv;
  const float* src = Wg + (size_t)hcol * KK;
  for (int k = threadIdx.x; k < KK; k += 256) Wcomb[(size_t)p * KK + k] = (__bf16)src[k];
  if (threadIdx.x == 0) biasp[p] = bg[hcol];
}

// xb[(t*64+b)*512 + k] = bf16(x[b][t][k])   (t-major rows for the recurrent A-fragments)
__global__ void k_convx(const float* x, __bf16* xb) {
  size_t idx = (size_t)blockIdx.x * 256 + threadIdx.x;  // 16,777,216
  int k = idx & 511;
  size_t row = idx >> 9;
  int t = (int)(row >> 6), b = (int)(row & 63);
  xb[idx] = (__bf16)x[((size_t)b * SS + t) * IN + k];
}

__global__ void k_convfc(const float* Wfc, __bf16* Wfcb) {
  size_t i = (size_t)blockIdx.x * 256 + threadIdx.x;  // 524,288
  Wfcb[i] = (__bf16)Wfc[i];
}

__global__ void k_zeroh0(__bf16* hsb) {
  size_t i = (size_t)blockIdx.x * 256 + threadIdx.x;  // 65,536 (slot 0 = h_{-1} = 0)
  hsb[i] = (__bf16)0.f;
}

__global__ void k_diag(float* out, float v) { out[0] = v; }

// Persistent recurrent kernel: 256 blocks x 256 thr (r5 structure, consolidated).
// - WT agent-scope h publication, per-wave vmcnt drain, per-block flags, wave0 poll.
// - ONE barrier/step: gt spill/act exchange is wave-local (wave w writes rows
//   16w..16w+15; act thread br=tid>>2 reads row br, br>>4 == tid>>6) -> lgkmcnt(0).
// - h-chunk loop start rotated by (n>>3)&15: co-XCD CUs first-touch different
//   lines -> stagger LLC-miss burst / L2 queueing of the broadcast.
__global__ __launch_bounds__(256) void k_lstm(const __bf16* __restrict__ Wcomb,
                                              const __bf16* __restrict__ xb,
                                              const float* __restrict__ biasp,
                                              __bf16* __restrict__ hsb,
                                              float* __restrict__ tail,
                                              unsigned* __restrict__ flags) {
  const int n = blockIdx.x;
  const int tid = threadIdx.x;
  const int w = tid >> 6, l = tid & 63;
  const int l16 = l & 15, lk = l >> 4;
  __shared__ __bf16 wl[48 * 512];   // 48 chunks x (4 lk x 16 cols x 8) bf16 = 49,152 B
  __shared__ float gt[64][20];      // MFMA D spill (stride 20: worst 2-way conflict = free)
  // --- preload weight slice into LDS, fragment-major ---
  for (int i = tid; i < COLS * (KK / 8); i += 256) {  // 16*192 = 3072
    int c = i / 192, kch = i % 192;
    bf16x8 v = *(const bf16x8*)(Wcomb + ((size_t)(n * COLS + c)) * KK + kch * 8);
    int chunk = kch >> 2, lkw = kch & 3;
    *(bf16x8*)(wl + ((chunk * 64 + lkw * 16 + c) << 3)) = v;
  }
  const int br = tid >> 2, rr = tid & 3;  // this thread's (batch, hcol-offset) element
  const float bias_f = biasp[n * COLS + 0 + rr];
  const float bias_i = biasp[n * COLS + 4 + rr];
  const float bias_o = biasp[n * COLS + 8 + rr];
  const float bias_c = biasp[n * COLS + 12 + rr];
  __syncthreads();
  const size_t aoffH = (size_t)(w * 16 + l16) * HH + lk * 8;
  const size_t aoffX = (size_t)(w * 16 + l16) * IN + lk * 8;
  const __bf16* wlane = wl + ((lk * 16 + l16) << 3);
  const int startC = (n >> 3) & 15;   // stagger key: co-XCD siblings differ
  const f32x4 vz = {0.f, 0.f, 0.f, 0.f};
  float cst = 0.f;
  for (int t = 0; t < SS; ++t) {
    const __bf16* hp = hsb + (size_t)t * (BB * HH);
    const __bf16* xp = xb + (size_t)t * (BB * IN);
    f32x4 a0 = vz, a1 = vz;
    // ---- phase A: x-part (no h dependency; overlaps other blocks' step-t tail) ----
#pragma unroll
    for (int kc = 0; kc < IN; kc += 64) {   // x-part: chunks 32..47
      bf16x8 av0 = *(const bf16x8*)(xp + aoffX + kc);
      bf16x8 av1 = *(const bf16x8*)(xp + aoffX + kc + 32);
      bf16x8 bv0 = *(const bf16x8*)(wlane + (32 + kc / 32) * 512);
      bf16x8 bv1 = *(const bf16x8*)(wlane + (33 + kc / 32) * 512);
      a0 = mfma16(av0, bv0, a0);
      a1 = mfma16(av1, bv1, a1);
    }
    // ---- phase B: wait until all 256 blocks have published h_t ----
    if (tid < 64) {
      const unsigned tgt = (unsigned)t;
      for (;;) {
        unsigned f0 = __hip_atomic_load(&flags[tid * 4 + 0], __ATOMIC_RELAXED, __HIP_MEMORY_SCOPE_AGENT);
        unsigned f1 = __hip_atomic_load(&flags[tid * 4 + 1], __ATOMIC_RELAXED, __HIP_MEMORY_SCOPE_AGENT);
        unsigned f2 = __hip_atomic_load(&flags[tid * 4 + 2], __ATOMIC_RELAXED, __HIP_MEMORY_SCOPE_AGENT);
        unsigned f3 = __hip_atomic_load(&flags[tid * 4 + 3], __ATOMIC_RELAXED, __HIP_MEMORY_SCOPE_AGENT);
        bool ok = (f0 >= tgt) & (f1 >= tgt) & (f2 >= tgt) & (f3 >= tgt);
        if (__all((int)ok)) break;
        __builtin_amdgcn_s_sleep(1);
      }
    }
    __syncthreads();
    asm volatile("" ::: "memory");  // no speculative h-load hoisting above the wait
    // ---- phase C: h-part, start rotated per block to stagger the broadcast burst ----
#pragma unroll
    for (int i = 0; i < 16; ++i) {
      int cc = (startC + i) & 15;       // 16 double-chunks of 64 k each
      int kc = cc * 64;
      bf16x8 av0 = *(const bf16x8*)(hp + aoffH + kc);
      bf16x8 av1 = *(const bf16x8*)(hp + aoffH + kc + 32);
      bf16x8 bv0 = *(const bf16x8*)(wlane + (cc * 2) * 512);
      bf16x8 bv1 = *(const bf16x8*)(wlane + (cc * 2 + 1) * 512);
      a0 = mfma16(av0, bv0, a0);
      a1 = mfma16(av1, bv1, a1);
    }
    f32x4 s = a0 + a1;
#pragma unroll
    for (int q = 0; q < 4; ++q) gt[w * 16 + lk * 4 + q][l16] = s[q];  // D: row=lk*4+q, col=l16
    // gt exchange is wave-local: wave w writes rows [16w,16w+16) and act reads exactly those.
    asm volatile("s_waitcnt lgkmcnt(0)" ::: "memory");
    // ---- phase D: activations + h/c update (parallel: 1 gate-set per thread) ----
    float f_ = gt[br][rr] + bias_f;
    float i_ = gt[br][4 + rr] + bias_i;
    float o_ = gt[br][8 + rr] + bias_o;
    float g_ = gt[br][12 + rr] + bias_c;
    cst = sigm(f_) * cst + sigm(i_) * tanh_f(g_);
    float hv = sigm(o_) * tanh_f(cst);
    const int hcol = n * HCPB + rr;
    // publish h as packed u32 agent-scope (sc1 write-through; never dirty in L2)
    unsigned hb = (unsigned)__builtin_bit_cast(unsigned short, (__bf16)hv);
    unsigned nb = __shfl_down(hb, 1);
    if ((rr & 1) == 0) {
      unsigned pk = hb | (nb << 16);
      unsigned* dst = (unsigned*)(hsb + (size_t)(t + 1) * (BB * HH) + (size_t)br * HH + hcol);
      __hip_atomic_store(dst, pk, __ATOMIC_RELAXED, __HIP_MEMORY_SCOPE_AGENT);
    }
    if (t == SS - 1) {
      tail[(size_t)br * HH + hcol] = hv;
      tail[(size_t)BB * HH + (size_t)br * HH + hcol] = cst;
    }
    // ---- phase E: arrive. Per-wave drain, one barrier, then flag. ----
    asm volatile("s_waitcnt vmcnt(0)" ::: "memory");
    __syncthreads();   // the only per-step block barrier
    if (t + 1 < SS && tid == 0)
      __hip_atomic_store(&flags[n], (unsigned)(t + 1), __ATOMIC_RELAXED, __HIP_MEMORY_SCOPE_AGENT);
  }
}

// GEMM-2: out[r=b*S+t][col] = hs[t+1][b][:] . Wfc[col][:] + bfc[col]  (M=32768,N=512,K=1024)
__global__ __launch_bounds__(256) void k_gemm_out(const __bf16* __restrict__ hsb,
                                                  const __bf16* __restrict__ Wfcb,
                                                  const float* __restrict__ bfc,
                                                  float* __restrict__ out) {
  int w = threadIdx.x >> 6, l = threadIdx.x & 63;
  int l16 = l & 15, lk = l >> 4;
  int Mbase = blockIdx.x * 64, Nbase = blockIdx.y * 64;
  int rA = Mbase + w * 16 + l16;
  int bb = rA >> 9, tt = rA & 511;
  const __bf16* Ap = hsb + ((size_t)(tt + 1) * BB + bb) * HH + lk * 8;
  const __bf16* Bp[4];
#pragma unroll
  for (int jt = 0; jt < 4; ++jt)
    Bp[jt] = Wfcb + ((size_t)(Nbase + jt * 16 + l16)) * HH + lk * 8;
  const f32x4 vz = {0.f, 0.f, 0.f, 0.f};
  f32x4 acc[4] = {vz, vz, vz, vz};
  for (int kc = 0; kc < HH; kc += 32) {
    bf16x8 a = *(const bf16x8*)(Ap + kc);
#pragma unroll
    for (int jt = 0; jt < 4; ++jt) {
      bf16x8 bv = *(const bf16x8*)(Bp[jt] + kc);
      acc[jt] = mfma16(a, bv, acc[jt]);
    }
  }
#pragma unroll
  for (int jt = 0; jt < 4; ++jt) {
    int col = Nbase + jt * 16 + l16;
    float badd = bfc[col];
#pragma unroll
    for (int q = 0; q < 4; ++q) {
      int rD = Mbase + w * 16 + lk * 4 + q;
      out[(size_t)rD * OO + col] = acc[jt][q] + badd;
    }
  }
}

extern "C" void kernel_launch(void* const* d_in, const int* in_sizes, int n_in,
                              void* d_out, int out_size, void* d_ws, size_t ws_size,
                              hipStream_t stream) {
  const float* x = (const float*)d_in[0];
  const float* Wf = (const float*)d_in[1];
  const float* Wi = (const float*)d_in[2];
  const float* Wo = (const float*)d_in[3];
  const float* Wc = (const float*)d_in[4];
  const float* bfv = (const float*)d_in[5];
  const float* biv = (const float*)d_in[6];
  const float* bov = (const float*)d_in[7];
  const float* bcv = (const float*)d_in[8];
  const float* Wfc = (const float*)d_in[9];
  const float* bfc = (const float*)d_in[10];
  float* out = (float*)d_out;

  char* ws = (char*)d_ws;
  size_t off = 0;
  auto take = [&](size_t bytes) -> char* {
    off = (off + 255) & ~(size_t)255;
    char* p = ws + off;
    off += bytes;
    return p;
  };
  __bf16* Wcomb = (__bf16*)take((size_t)G4 * KK * 2);            // 12 MB
  __bf16* Wfcb = (__bf16*)take((size_t)OO * HH * 2);             // 1 MB
  float* biasp = (float*)take((size_t)G4 * 4);                   // 16 KB
  unsigned* flags = (unsigned*)take(NBLK * 4);                   // per-block flags (1 KB)
  __bf16* xb = (__bf16*)take((size_t)BB * SS * IN * 2);          // 32 MB
  __bf16* hsb = (__bf16*)take((size_t)(SS + 1) * BB * HH * 2);   // 64.1 MB
  if (off > ws_size) {
    hipLaunchKernelGGL(k_diag, dim3(1), dim3(1), 0, stream, out,
                       1.0e6f + (float)(ws_size >> 20));
    return;
  }

  hipMemsetAsync(flags, 0, NBLK * 4, stream);  // reset flags each launch (graph-replay-safe)
  hipLaunchKernelGGL(k_convw, dim3(G4), dim3(256), 0, stream,
                     Wf, Wi, Wo, Wc, bfv, biv, bov, bcv, Wcomb, biasp);
  hipLaunchKernelGGL(k_convx, dim3((BB * SS * IN) / 256), dim3(256), 0, stream, x, xb);
  hipLaunchKernelGGL(k_convfc, dim3((OO * HH) / 256), dim3(256), 0, stream, Wfc, Wfcb);
  hipLaunchKernelGGL(k_zeroh0, dim3((BB * HH) / 256), dim3(256), 0, stream, hsb);

  float* tail = out + (size_t)BB * SS * OO;
  void* args[] = {(void*)&Wcomb, (void*)&xb, (void*)&biasp, (void*)&hsb,
                  (void*)&tail, (void*)&flags};
  hipError_t cerr = hipLaunchCooperativeKernel((const void*)k_lstm, dim3(NBLK), dim3(256),
                                               args, 0, stream);
  if (cerr != hipSuccess) {
    hipLaunchKernelGGL(k_diag, dim3(1), dim3(1), 0, stream, out,
                       2.0e6f + (float)(int)cerr);
    return;
  }

  hipLaunchKernelGGL(k_gemm_out, dim3((BB * SS) / 64, OO / 64), dim3(256), 0, stream,
                     hsb, Wfcb, bfc, out);
}